// Round 3
// baseline (594.712 us; speedup 1.0000x reference)
//
#include <hip/hip_runtime.h>

typedef unsigned short u16;
typedef __attribute__((ext_vector_type(8))) __bf16 bf16x8;
typedef __attribute__((ext_vector_type(8))) unsigned short u16x8;
typedef __attribute__((ext_vector_type(4))) float f32x4;

#define BK 32

__device__ __forceinline__ u16 f32_to_bf16(float f) {
  unsigned int u = __builtin_bit_cast(unsigned int, f);
  u += 0x7fffu + ((u >> 16) & 1u);
  return (u16)(u >> 16);
}

// ---------------- fp32 -> bf16 conversion ----------------
__global__ __launch_bounds__(256) void cvt_bf16(const float* __restrict__ in,
                                                u16* __restrict__ out, int n) {
  int i = (blockIdx.x * 256 + threadIdx.x) * 4;
  if (i >= n) return;
  float4 v = *(const float4*)(in + i);
  ushort4 o;
  o.x = f32_to_bf16(v.x);
  o.y = f32_to_bf16(v.y);
  o.z = f32_to_bf16(v.z);
  o.w = f32_to_bf16(v.w);
  *(ushort4*)(out + i) = o;
}

// ---------------- shared GEMM core: C(128x128) = A(MxK) * B(NxK)^T ----------
// Register staging (u16x8 load -> ds_write_b128).
__device__ __forceinline__ void gemm_core(const u16* __restrict__ A,
                                          const u16* __restrict__ B, int K,
                                          u16* As, u16* Bs, f32x4 acc[4][4]) {
  const int tid = threadIdx.x;
  const int w = tid >> 6, lane = tid & 63;
  const int wm = (w >> 1) << 6, wn = (w & 1) << 6;
  const int quad = lane >> 4, l15 = lane & 15;
  const int bm = blockIdx.y, bn = blockIdx.x;

  // thread tid stages row tid>>2 (and +64), 16B chunk tid&3 of the 64B row
  const int a0 = (bm * 128 + (tid >> 2)) * K + (tid & 3) * 8;
  const int a1 = a0 + 64 * K;
  const int b0 = (bn * 128 + (tid >> 2)) * K + (tid & 3) * 8;
  const int b1 = b0 + 64 * K;

  for (int k0 = 0; k0 < K; k0 += BK) {
    u16x8 va0 = *(const u16x8*)(A + a0 + k0);
    u16x8 va1 = *(const u16x8*)(A + a1 + k0);
    u16x8 vb0 = *(const u16x8*)(B + b0 + k0);
    u16x8 vb1 = *(const u16x8*)(B + b1 + k0);
    __syncthreads();
    *(u16x8*)(As + tid * 8) = va0;          // row tid>>2, cols (tid&3)*8..+8
    *(u16x8*)(As + (256 + tid) * 8) = va1;  // row 64 + tid>>2
    *(u16x8*)(Bs + tid * 8) = vb0;
    *(u16x8*)(Bs + (256 + tid) * 8) = vb1;
    __syncthreads();
    bf16x8 af[4], bf[4];
#pragma unroll
    for (int i = 0; i < 4; i++)
      af[i] = *(const bf16x8*)(As + (wm + i * 16 + l15) * BK + quad * 8);
#pragma unroll
    for (int j = 0; j < 4; j++)
      bf[j] = *(const bf16x8*)(Bs + (wn + j * 16 + l15) * BK + quad * 8);
#pragma unroll
    for (int i = 0; i < 4; i++)
#pragma unroll
      for (int j = 0; j < 4; j++)
        acc[i][j] =
            __builtin_amdgcn_mfma_f32_16x16x32_bf16(af[i], bf[j], acc[i][j], 0, 0, 0);
  }
}

// ---------------- GEMM with bf16 output (q, latent) ----------------
__global__ __launch_bounds__(256) void gemm_bf16out(const u16* __restrict__ A,
                                                    const u16* __restrict__ B,
                                                    const float* __restrict__ bias,
                                                    u16* __restrict__ C, int K, int N) {
  __shared__ __align__(16) u16 As[128 * BK];
  __shared__ __align__(16) u16 Bs[128 * BK];
  f32x4 acc[4][4];
  const f32x4 z = {0.f, 0.f, 0.f, 0.f};
#pragma unroll
  for (int i = 0; i < 4; i++)
#pragma unroll
    for (int j = 0; j < 4; j++) acc[i][j] = z;
  gemm_core(A, B, K, As, Bs, acc);

  const int tid = threadIdx.x;
  const int w = tid >> 6, lane = tid & 63;
  const int wm = (w >> 1) << 6, wn = (w & 1) << 6;
  const int quad = lane >> 4, l15 = lane & 15;
  const int row0 = blockIdx.y * 128 + wm + quad * 4;
  const int col0 = blockIdx.x * 128 + wn + l15;
#pragma unroll
  for (int i = 0; i < 4; i++)
#pragma unroll
    for (int j = 0; j < 4; j++) {
      int col = col0 + j * 16;
      float bv = bias[col];
#pragma unroll
      for (int r = 0; r < 4; r++) {
        int row = row0 + i * 16 + r;
        C[(size_t)row * N + col] = f32_to_bf16(acc[i][j][r] + bv);
      }
    }
}

// ---------------- GEMM with fp32 output (final projection) ----------------
__global__ __launch_bounds__(256) void gemm_f32out(const u16* __restrict__ A,
                                                   const u16* __restrict__ B,
                                                   const float* __restrict__ bias,
                                                   float* __restrict__ C, int K, int N) {
  __shared__ __align__(16) u16 As[128 * BK];
  __shared__ __align__(16) u16 Bs[128 * BK];
  f32x4 acc[4][4];
  const f32x4 z = {0.f, 0.f, 0.f, 0.f};
#pragma unroll
  for (int i = 0; i < 4; i++)
#pragma unroll
    for (int j = 0; j < 4; j++) acc[i][j] = z;
  gemm_core(A, B, K, As, Bs, acc);

  const int tid = threadIdx.x;
  const int w = tid >> 6, lane = tid & 63;
  const int wm = (w >> 1) << 6, wn = (w & 1) << 6;
  const int quad = lane >> 4, l15 = lane & 15;
  const int row0 = blockIdx.y * 128 + wm + quad * 4;
  const int col0 = blockIdx.x * 128 + wn + l15;
#pragma unroll
  for (int i = 0; i < 4; i++)
#pragma unroll
    for (int j = 0; j < 4; j++) {
      int col = col0 + j * 16;
      float bv = bias[col];
#pragma unroll
      for (int r = 0; r < 4; r++) {
        int row = row0 + i * 16 + r;
        C[(size_t)row * N + col] = acc[i][j][r] + bv;
      }
    }
}

// ------------- GEMM3: kv-up with scatter epilogue: K->(b,h,s,d), V->(b,h,d,s) -
__global__ __launch_bounds__(256) void gemm_kv(const u16* __restrict__ A,
                                               const u16* __restrict__ B,
                                               const float* __restrict__ bias,
                                               u16* __restrict__ Khat,
                                               u16* __restrict__ Vt, int K) {
  __shared__ __align__(16) u16 As[128 * BK];
  __shared__ __align__(16) u16 Bs[128 * BK];
  f32x4 acc[4][4];
  const f32x4 z = {0.f, 0.f, 0.f, 0.f};
#pragma unroll
  for (int i = 0; i < 4; i++)
#pragma unroll
    for (int j = 0; j < 4; j++) acc[i][j] = z;
  gemm_core(A, B, K, As, Bs, acc);

  const int tid = threadIdx.x;
  const int w = tid >> 6, lane = tid & 63;
  const int wm = (w >> 1) << 6, wn = (w & 1) << 6;
  const int quad = lane >> 4, l15 = lane & 15;
  const int row0 = blockIdx.y * 128 + wm + quad * 4;
  const int col0 = blockIdx.x * 128 + wn + l15;
#pragma unroll
  for (int i = 0; i < 4; i++)
#pragma unroll
    for (int j = 0; j < 4; j++) {
      int n = col0 + j * 16;
      float bv = bias[n];
#pragma unroll
      for (int r = 0; r < 4; r++) {
        int row = row0 + i * 16 + r;   // row = b*2048 + s
        int bb = row >> 11, s = row & 2047;
        u16 val = f32_to_bf16(acc[i][j][r] + bv);
        if (n < 2048) {  // K half (uniform per block: 128 | 2048)
          int h = n >> 7, d = n & 127;
          Khat[((size_t)(bb * 16 + h) * 2048 + s) * 128 + d] = val;
        } else {         // V half, transposed
          int h = (n - 2048) >> 7, d = n & 127;
          Vt[((size_t)(bb * 16 + h) * 128 + d) * 2048 + s] = val;
        }
      }
    }
}

// ---------------- attention: flash-style, no score materialization ----------
// grid = 2 (b) * 16 (h) * 32 (q-tiles of 64). 4 waves, each owns 16 Q rows.
__global__ __launch_bounds__(256) void attn_kernel(const u16* __restrict__ Q,
                                                   const u16* __restrict__ Khat,
                                                   const u16* __restrict__ Vt,
                                                   u16* __restrict__ O) {
  __shared__ __align__(16) u16 Ks[64 * 136];     // keys x dims, padded stride
  __shared__ __align__(16) u16 Vs[128 * 72];     // dims x keys, padded stride
  __shared__ __align__(16) u16 Ps[4 * 16 * 72];  // per-wave P (16 rows x 64 keys)

  const int tid = threadIdx.x;
  const int w = tid >> 6, lane = tid & 63;
  const int quad = lane >> 4, l15 = lane & 15;
  const int qb = blockIdx.x & 31;
  const int h = (blockIdx.x >> 5) & 15;
  const int b = blockIdx.x >> 9;
  const int bh = b * 16 + h;
  const float SC = 0.08838834764831845f * 1.4426950408889634f;  // 1/sqrt(128)*log2(e)

  // Q fragments: A-layout (m=lane&15, k=quad*8+j), rows = this wave's 16 rows
  bf16x8 qf[4];
  {
    const u16* qrow =
        Q + (size_t)(b * 2048 + qb * 64 + w * 16 + l15) * 2048 + h * 128 + quad * 8;
#pragma unroll
    for (int kc = 0; kc < 4; kc++) qf[kc] = *(const bf16x8*)(qrow + kc * 32);
  }

  f32x4 oacc[8];
  const f32x4 z = {0.f, 0.f, 0.f, 0.f};
#pragma unroll
  for (int nt = 0; nt < 8; nt++) oacc[nt] = z;
  float lsum[4] = {0.f, 0.f, 0.f, 0.f};

  const u16* Kg = Khat + (size_t)bh * 2048 * 128;
  const u16* Vg = Vt + (size_t)bh * 128 * 2048;
  u16* Pw = Ps + w * 16 * 72;

  for (int key0 = 0; key0 < 2048; key0 += 64) {
    __syncthreads();
    // stage K chunk: 64 keys x 128 dims = 1024 16B chunks (FIX: was 512 ->
    // dims 64..127 never written, QK^T read stale LDS)
#pragma unroll
    for (int it = 0; it < 4; it++) {
      int slot = it * 256 + tid;
      int kr = slot >> 4, c = slot & 15;
      u16x8 v = *(const u16x8*)(Kg + (size_t)(key0 + kr) * 128 + c * 8);
      *(u16x8*)(Ks + kr * 136 + c * 8) = v;
    }
    // stage Vt chunk: 128 dims x 64 keys = 1024 16B chunks
#pragma unroll
    for (int it = 0; it < 4; it++) {
      int slot = it * 256 + tid;
      int d = slot >> 3, c = slot & 7;
      u16x8 v = *(const u16x8*)(Vg + (size_t)d * 2048 + key0 + c * 8);
      *(u16x8*)(Vs + d * 72 + c * 8) = v;
    }
    __syncthreads();

    // S = Q K^T  (16 rows x 64 keys)
    f32x4 sacc[4];
#pragma unroll
    for (int nt = 0; nt < 4; nt++) sacc[nt] = z;
#pragma unroll
    for (int nt = 0; nt < 4; nt++)
#pragma unroll
      for (int kc = 0; kc < 4; kc++) {
        bf16x8 kf = *(const bf16x8*)(Ks + (nt * 16 + l15) * 136 + kc * 32 + quad * 8);
        sacc[nt] =
            __builtin_amdgcn_mfma_f32_16x16x32_bf16(qf[kc], kf, sacc[nt], 0, 0, 0);
      }

    // P = exp(S*scale); row sums; C-layout -> A-layout via per-wave LDS
#pragma unroll
    for (int nt = 0; nt < 4; nt++)
#pragma unroll
      for (int r = 0; r < 4; r++) {
        float e = exp2f(sacc[nt][r] * SC);
        lsum[r] += e;
        Pw[(quad * 4 + r) * 72 + nt * 16 + l15] = f32_to_bf16(e);
      }

    // O += P * V
#pragma unroll
    for (int kc = 0; kc < 2; kc++) {
      bf16x8 pf = *(const bf16x8*)(Pw + l15 * 72 + kc * 32 + quad * 8);
#pragma unroll
      for (int nt = 0; nt < 8; nt++) {
        bf16x8 vf = *(const bf16x8*)(Vs + (nt * 16 + l15) * 72 + kc * 32 + quad * 8);
        oacc[nt] =
            __builtin_amdgcn_mfma_f32_16x16x32_bf16(pf, vf, oacc[nt], 0, 0, 0);
      }
    }
  }

  // reduce row sums across the 16 lanes of each quad group
#pragma unroll
  for (int r = 0; r < 4; r++) {
    float s = lsum[r];
    s += __shfl_xor(s, 1);
    s += __shfl_xor(s, 2);
    s += __shfl_xor(s, 4);
    s += __shfl_xor(s, 8);
    lsum[r] = 1.0f / s;
  }

  // normalize + store (plain (b*2048+s, 2048) layout for final GEMM)
#pragma unroll
  for (int nt = 0; nt < 8; nt++)
#pragma unroll
    for (int r = 0; r < 4; r++) {
      int row = b * 2048 + qb * 64 + w * 16 + quad * 4 + r;
      int col = h * 128 + nt * 16 + l15;
      O[(size_t)row * 2048 + col] = f32_to_bf16(oacc[nt][r] * lsum[r]);
    }
}

// ---------------- launch ----------------
extern "C" void kernel_launch(void* const* d_in, const int* in_sizes, int n_in,
                              void* d_out, int out_size, void* d_ws, size_t ws_size,
                              hipStream_t stream) {
  (void)in_sizes; (void)n_in; (void)out_size; (void)ws_size;
  const float* x     = (const float*)d_in[0];
  const float* q_w   = (const float*)d_in[1];
  const float* q_b   = (const float*)d_in[2];
  const float* kvd_w = (const float*)d_in[3];
  const float* kvd_b = (const float*)d_in[4];
  const float* kvu_w = (const float*)d_in[5];
  const float* kvu_b = (const float*)d_in[6];
  const float* out_w = (const float*)d_in[7];
  const float* out_b = (const float*)d_in[8];
  float* out = (float*)d_out;

  // Workspace layout (94 MB peak, with aliasing):
  //   X    [0,16MB)   x_bf; later reused for outw_bf (8MB)
  //   W1   [16,24MB)  qw_bf; later reused for kvuw_bf (4MB)
  //   W2   [24,26MB)  kvdw_bf
  //   Q    [26,42MB)  qbuf
  //   Lat  [42,46MB)  latent
  //   Khat [46,62MB)
  //   Vt   [62,78MB)
  //   AO   [78,94MB)
  char* p = (char*)d_ws;
  u16* X    = (u16*)(p + 0);
  u16* W1   = (u16*)(p + (size_t)16 * 1024 * 1024);
  u16* W2   = (u16*)(p + (size_t)24 * 1024 * 1024);
  u16* Qb   = (u16*)(p + (size_t)26 * 1024 * 1024);
  u16* Lat  = (u16*)(p + (size_t)42 * 1024 * 1024);
  u16* Khat = (u16*)(p + (size_t)46 * 1024 * 1024);
  u16* Vt   = (u16*)(p + (size_t)62 * 1024 * 1024);
  u16* AO   = (u16*)(p + (size_t)78 * 1024 * 1024);

  cvt_bf16<<<dim3(8192), dim3(256), 0, stream>>>(x, X, 8388608);
  cvt_bf16<<<dim3(4096), dim3(256), 0, stream>>>(q_w, W1, 4194304);
  cvt_bf16<<<dim3(1024), dim3(256), 0, stream>>>(kvd_w, W2, 1048576);

  // q = x @ q_w^T + q_b          (4096x2048, K=2048)
  gemm_bf16out<<<dim3(16, 32), dim3(256), 0, stream>>>(X, W1, q_b, Qb, 2048, 2048);
  // latent = x @ kvd_w^T + kvd_b (4096x512, K=2048)
  gemm_bf16out<<<dim3(4, 32), dim3(256), 0, stream>>>(X, W2, kvd_b, Lat, 2048, 512);

  cvt_bf16<<<dim3(2048), dim3(256), 0, stream>>>(kvu_w, W1, 2097152);  // reuse W1
  // kv = latent @ kvu_w^T + kvu_b -> Khat (b,h,s,d) / Vt (b,h,d,s)
  gemm_kv<<<dim3(32, 32), dim3(256), 0, stream>>>(Lat, W1, kvu_b, Khat, Vt, 512);

  cvt_bf16<<<dim3(4096), dim3(256), 0, stream>>>(out_w, X, 4194304);   // reuse X
  // attention
  attn_kernel<<<dim3(1024), dim3(256), 0, stream>>>(Qb, Khat, Vt, AO);
  // final projection (fp32 out)
  gemm_f32out<<<dim3(16, 32), dim3(256), 0, stream>>>(AO, X, out_b, out, 2048, 2048);
}

// Round 4
// 445.163 us; speedup vs baseline: 1.3359x; 1.3359x over previous
//
#include <hip/hip_runtime.h>

typedef unsigned short u16;
typedef __attribute__((ext_vector_type(8))) __bf16 bf16x8;
typedef __attribute__((ext_vector_type(8))) unsigned short u16x8;
typedef __attribute__((ext_vector_type(4))) float f32x4;
typedef __attribute__((ext_vector_type(16))) float f32x16;

#define BK 32

__device__ __forceinline__ u16 f32_to_bf16(float f) {
  unsigned int u = __builtin_bit_cast(unsigned int, f);
  u += 0x7fffu + ((u >> 16) & 1u);
  return (u16)(u >> 16);
}

// ---------------- fp32 -> bf16 conversion ----------------
__global__ __launch_bounds__(256) void cvt_bf16(const float* __restrict__ in,
                                                u16* __restrict__ out, int n) {
  int i = (blockIdx.x * 256 + threadIdx.x) * 4;
  if (i >= n) return;
  float4 v = *(const float4*)(in + i);
  ushort4 o;
  o.x = f32_to_bf16(v.x);
  o.y = f32_to_bf16(v.y);
  o.z = f32_to_bf16(v.z);
  o.w = f32_to_bf16(v.w);
  *(ushort4*)(out + i) = o;
}

// ---------------- shared GEMM core: C(128x128) = A(MxK) * B(NxK)^T ----------
__device__ __forceinline__ void gemm_core(const u16* __restrict__ A,
                                          const u16* __restrict__ B, int K,
                                          u16* As, u16* Bs, f32x4 acc[4][4]) {
  const int tid = threadIdx.x;
  const int w = tid >> 6, lane = tid & 63;
  const int wm = (w >> 1) << 6, wn = (w & 1) << 6;
  const int quad = lane >> 4, l15 = lane & 15;
  const int bm = blockIdx.y, bn = blockIdx.x;

  const int a0 = (bm * 128 + (tid >> 2)) * K + (tid & 3) * 8;
  const int a1 = a0 + 64 * K;
  const int b0 = (bn * 128 + (tid >> 2)) * K + (tid & 3) * 8;
  const int b1 = b0 + 64 * K;

  for (int k0 = 0; k0 < K; k0 += BK) {
    u16x8 va0 = *(const u16x8*)(A + a0 + k0);
    u16x8 va1 = *(const u16x8*)(A + a1 + k0);
    u16x8 vb0 = *(const u16x8*)(B + b0 + k0);
    u16x8 vb1 = *(const u16x8*)(B + b1 + k0);
    __syncthreads();
    *(u16x8*)(As + tid * 8) = va0;
    *(u16x8*)(As + (256 + tid) * 8) = va1;
    *(u16x8*)(Bs + tid * 8) = vb0;
    *(u16x8*)(Bs + (256 + tid) * 8) = vb1;
    __syncthreads();
    bf16x8 af[4], bf[4];
#pragma unroll
    for (int i = 0; i < 4; i++)
      af[i] = *(const bf16x8*)(As + (wm + i * 16 + l15) * BK + quad * 8);
#pragma unroll
    for (int j = 0; j < 4; j++)
      bf[j] = *(const bf16x8*)(Bs + (wn + j * 16 + l15) * BK + quad * 8);
#pragma unroll
    for (int i = 0; i < 4; i++)
#pragma unroll
      for (int j = 0; j < 4; j++)
        acc[i][j] =
            __builtin_amdgcn_mfma_f32_16x16x32_bf16(af[i], bf[j], acc[i][j], 0, 0, 0);
  }
}

// ---------------- GEMM with bf16 output (q, latent) ----------------
__global__ __launch_bounds__(256) void gemm_bf16out(const u16* __restrict__ A,
                                                    const u16* __restrict__ B,
                                                    const float* __restrict__ bias,
                                                    u16* __restrict__ C, int K, int N) {
  __shared__ __align__(16) u16 As[128 * BK];
  __shared__ __align__(16) u16 Bs[128 * BK];
  f32x4 acc[4][4];
  const f32x4 z = {0.f, 0.f, 0.f, 0.f};
#pragma unroll
  for (int i = 0; i < 4; i++)
#pragma unroll
    for (int j = 0; j < 4; j++) acc[i][j] = z;
  gemm_core(A, B, K, As, Bs, acc);

  const int tid = threadIdx.x;
  const int w = tid >> 6, lane = tid & 63;
  const int wm = (w >> 1) << 6, wn = (w & 1) << 6;
  const int quad = lane >> 4, l15 = lane & 15;
  const int row0 = blockIdx.y * 128 + wm + quad * 4;
  const int col0 = blockIdx.x * 128 + wn + l15;
#pragma unroll
  for (int i = 0; i < 4; i++)
#pragma unroll
    for (int j = 0; j < 4; j++) {
      int col = col0 + j * 16;
      float bv = bias[col];
#pragma unroll
      for (int r = 0; r < 4; r++) {
        int row = row0 + i * 16 + r;
        C[(size_t)row * N + col] = f32_to_bf16(acc[i][j][r] + bv);
      }
    }
}

// ---------------- GEMM with fp32 output (final projection) ----------------
__global__ __launch_bounds__(256) void gemm_f32out(const u16* __restrict__ A,
                                                   const u16* __restrict__ B,
                                                   const float* __restrict__ bias,
                                                   float* __restrict__ C, int K, int N) {
  __shared__ __align__(16) u16 As[128 * BK];
  __shared__ __align__(16) u16 Bs[128 * BK];
  f32x4 acc[4][4];
  const f32x4 z = {0.f, 0.f, 0.f, 0.f};
#pragma unroll
  for (int i = 0; i < 4; i++)
#pragma unroll
    for (int j = 0; j < 4; j++) acc[i][j] = z;
  gemm_core(A, B, K, As, Bs, acc);

  const int tid = threadIdx.x;
  const int w = tid >> 6, lane = tid & 63;
  const int wm = (w >> 1) << 6, wn = (w & 1) << 6;
  const int quad = lane >> 4, l15 = lane & 15;
  const int row0 = blockIdx.y * 128 + wm + quad * 4;
  const int col0 = blockIdx.x * 128 + wn + l15;
#pragma unroll
  for (int i = 0; i < 4; i++)
#pragma unroll
    for (int j = 0; j < 4; j++) {
      int col = col0 + j * 16;
      float bv = bias[col];
#pragma unroll
      for (int r = 0; r < 4; r++) {
        int row = row0 + i * 16 + r;
        C[(size_t)row * N + col] = acc[i][j][r] + bv;
      }
    }
}

// ------------- GEMM3: kv-up with scatter epilogue: K->(b,h,s,d), V->(b,h,d,s) -
__global__ __launch_bounds__(256) void gemm_kv(const u16* __restrict__ A,
                                               const u16* __restrict__ B,
                                               const float* __restrict__ bias,
                                               u16* __restrict__ Khat,
                                               u16* __restrict__ Vt, int K) {
  __shared__ __align__(16) u16 As[128 * BK];
  __shared__ __align__(16) u16 Bs[128 * BK];
  f32x4 acc[4][4];
  const f32x4 z = {0.f, 0.f, 0.f, 0.f};
#pragma unroll
  for (int i = 0; i < 4; i++)
#pragma unroll
    for (int j = 0; j < 4; j++) acc[i][j] = z;
  gemm_core(A, B, K, As, Bs, acc);

  const int tid = threadIdx.x;
  const int w = tid >> 6, lane = tid & 63;
  const int wm = (w >> 1) << 6, wn = (w & 1) << 6;
  const int quad = lane >> 4, l15 = lane & 15;
  const int row0 = blockIdx.y * 128 + wm + quad * 4;
  const int col0 = blockIdx.x * 128 + wn + l15;
#pragma unroll
  for (int i = 0; i < 4; i++)
#pragma unroll
    for (int j = 0; j < 4; j++) {
      int n = col0 + j * 16;
      float bv = bias[n];
#pragma unroll
      for (int r = 0; r < 4; r++) {
        int row = row0 + i * 16 + r;   // row = b*2048 + s
        int bb = row >> 11, s = row & 2047;
        u16 val = f32_to_bf16(acc[i][j][r] + bv);
        if (n < 2048) {
          int h = n >> 7, d = n & 127;
          Khat[((size_t)(bb * 16 + h) * 2048 + s) * 128 + d] = val;
        } else {
          int h = (n - 2048) >> 7, d = n & 127;
          Vt[((size_t)(bb * 16 + h) * 128 + d) * 2048 + s] = val;
        }
      }
    }
}

// ---------------- attention: 32-row waves, 32x32x16 MFMA, Q in registers ----
// grid = 2 (b) * 16 (h) * 16 (q-tiles of 128). 4 waves, each owns 32 Q rows.
__global__ __launch_bounds__(256) void attn_kernel(const u16* __restrict__ Q,
                                                   const u16* __restrict__ Khat,
                                                   const u16* __restrict__ Vt,
                                                   u16* __restrict__ O) {
  __shared__ __align__(16) u16 Ks[64 * 136];      // keys x dims (stride 136)
  __shared__ __align__(16) u16 Vs[128 * 72];      // dims x keys (stride 72)
  __shared__ __align__(16) u16 Ps[4 * 32 * 72];   // per-wave P (32 rows x 64 keys)

  const int tid = threadIdx.x;
  const int w = tid >> 6, lane = tid & 63;
  const int l31 = lane & 31, half = lane >> 5;
  const int qt = blockIdx.x & 15;
  const int h = (blockIdx.x >> 4) & 15;
  const int b = blockIdx.x >> 8;
  const int bh = b * 16 + h;
  const float SC = 0.08838834764831845f * 1.4426950408889634f;  // 1/sqrt(128)*log2(e)

  // Q fragments in registers: A-layout for 32x32x16 (m=lane&31, k=half*8+j)
  // wave's rows: qt*128 + w*32 + l31; K = head dim 128 -> 8 frags
  bf16x8 qf[8];
  {
    const u16* qrow = Q + (size_t)(b * 2048 + qt * 128 + w * 32 + l31) * 2048 +
                      h * 128 + half * 8;
#pragma unroll
    for (int kc = 0; kc < 8; kc++) qf[kc] = *(const bf16x8*)(qrow + kc * 16);
  }

  f32x16 oacc[4];
#pragma unroll
  for (int nt = 0; nt < 4; nt++)
#pragma unroll
    for (int r = 0; r < 16; r++) oacc[nt][r] = 0.f;
  float lsum[16];
#pragma unroll
  for (int r = 0; r < 16; r++) lsum[r] = 0.f;

  const u16* Kg = Khat + (size_t)bh * 2048 * 128;
  const u16* Vg = Vt + (size_t)bh * 128 * 2048;
  u16* Pw = Ps + w * 32 * 72;

  for (int key0 = 0; key0 < 2048; key0 += 64) {
    // global loads into regs first (8 x 16B per thread)
    u16x8 kv[4], vv[4];
#pragma unroll
    for (int it = 0; it < 4; it++) {
      int slot = it * 256 + tid;
      int kr = slot >> 4, c = slot & 15;                       // 16 chunks/key-row
      kv[it] = *(const u16x8*)(Kg + (size_t)(key0 + kr) * 128 + c * 8);
    }
#pragma unroll
    for (int it = 0; it < 4; it++) {
      int slot = it * 256 + tid;
      int d = slot >> 3, c = slot & 7;                         // 8 chunks/dim-row
      vv[it] = *(const u16x8*)(Vg + (size_t)d * 2048 + key0 + c * 8);
    }
    __syncthreads();   // all waves done reading previous Ks/Vs
#pragma unroll
    for (int it = 0; it < 4; it++) {
      int slot = it * 256 + tid;
      int kr = slot >> 4, c = slot & 15;
      *(u16x8*)(Ks + kr * 136 + c * 8) = kv[it];
    }
#pragma unroll
    for (int it = 0; it < 4; it++) {
      int slot = it * 256 + tid;
      int d = slot >> 3, c = slot & 7;
      *(u16x8*)(Vs + d * 72 + c * 8) = vv[it];
    }
    __syncthreads();

    // S = Q K^T : 32 rows x 64 keys = 2 col-tiles of 32, K=128 (8 k-steps)
    f32x16 sacc[2];
#pragma unroll
    for (int ct = 0; ct < 2; ct++)
#pragma unroll
      for (int r = 0; r < 16; r++) sacc[ct][r] = 0.f;
#pragma unroll
    for (int ct = 0; ct < 2; ct++)
#pragma unroll
      for (int kc = 0; kc < 8; kc++) {
        bf16x8 kf =
            *(const bf16x8*)(Ks + (ct * 32 + l31) * 136 + kc * 16 + half * 8);
        sacc[ct] =
            __builtin_amdgcn_mfma_f32_32x32x16_bf16(qf[kc], kf, sacc[ct], 0, 0, 0);
      }

    // P = exp2(S*SC); accumulate per-row partial sums; write C->A via LDS
    // C layout 32x32: col=l31, row = (reg&3) + 8*(reg>>2) + 4*half
#pragma unroll
    for (int ct = 0; ct < 2; ct++)
#pragma unroll
      for (int r = 0; r < 16; r++) {
        float e = exp2f(sacc[ct][r] * SC);
        lsum[r] += e;
        int ridx = (r & 3) + 8 * (r >> 2) + 4 * half;
        Pw[ridx * 72 + ct * 32 + l31] = f32_to_bf16(e);
      }

    // O += P V : A = P (m=row, k=key), B = Vs (n=dim, k=key)
    bf16x8 pf[4];
#pragma unroll
    for (int kc = 0; kc < 4; kc++)
      pf[kc] = *(const bf16x8*)(Pw + l31 * 72 + kc * 16 + half * 8);
#pragma unroll
    for (int nt = 0; nt < 4; nt++)
#pragma unroll
      for (int kc = 0; kc < 4; kc++) {
        bf16x8 vf =
            *(const bf16x8*)(Vs + (nt * 32 + l31) * 72 + kc * 16 + half * 8);
        oacc[nt] =
            __builtin_amdgcn_mfma_f32_32x32x16_bf16(pf[kc], vf, oacc[nt], 0, 0, 0);
      }
  }

  // reduce row sums across the 32 lanes of each half (cols 0..31, both cts
  // already accumulated in-register)
#pragma unroll
  for (int r = 0; r < 16; r++) {
    float s = lsum[r];
    s += __shfl_xor(s, 1);
    s += __shfl_xor(s, 2);
    s += __shfl_xor(s, 4);
    s += __shfl_xor(s, 8);
    s += __shfl_xor(s, 16);
    lsum[r] = 1.0f / s;
  }

  // normalize + store: row = (r&3)+8*(r>>2)+4*half, col(dim) = nt*32+l31
#pragma unroll
  for (int nt = 0; nt < 4; nt++)
#pragma unroll
    for (int r = 0; r < 16; r++) {
      int ridx = (r & 3) + 8 * (r >> 2) + 4 * half;
      int row = b * 2048 + qt * 128 + w * 32 + ridx;
      int col = h * 128 + nt * 32 + l31;
      O[(size_t)row * 2048 + col] = f32_to_bf16(oacc[nt][r] * lsum[r]);
    }
}

// ---------------- launch ----------------
extern "C" void kernel_launch(void* const* d_in, const int* in_sizes, int n_in,
                              void* d_out, int out_size, void* d_ws, size_t ws_size,
                              hipStream_t stream) {
  (void)in_sizes; (void)n_in; (void)out_size; (void)ws_size;
  const float* x     = (const float*)d_in[0];
  const float* q_w   = (const float*)d_in[1];
  const float* q_b   = (const float*)d_in[2];
  const float* kvd_w = (const float*)d_in[3];
  const float* kvd_b = (const float*)d_in[4];
  const float* kvu_w = (const float*)d_in[5];
  const float* kvu_b = (const float*)d_in[6];
  const float* out_w = (const float*)d_in[7];
  const float* out_b = (const float*)d_in[8];
  float* out = (float*)d_out;

  char* p = (char*)d_ws;
  u16* X    = (u16*)(p + 0);
  u16* W1   = (u16*)(p + (size_t)16 * 1024 * 1024);
  u16* W2   = (u16*)(p + (size_t)24 * 1024 * 1024);
  u16* Qb   = (u16*)(p + (size_t)26 * 1024 * 1024);
  u16* Lat  = (u16*)(p + (size_t)42 * 1024 * 1024);
  u16* Khat = (u16*)(p + (size_t)46 * 1024 * 1024);
  u16* Vt   = (u16*)(p + (size_t)62 * 1024 * 1024);
  u16* AO   = (u16*)(p + (size_t)78 * 1024 * 1024);

  cvt_bf16<<<dim3(8192), dim3(256), 0, stream>>>(x, X, 8388608);
  cvt_bf16<<<dim3(4096), dim3(256), 0, stream>>>(q_w, W1, 4194304);
  cvt_bf16<<<dim3(1024), dim3(256), 0, stream>>>(kvd_w, W2, 1048576);

  gemm_bf16out<<<dim3(16, 32), dim3(256), 0, stream>>>(X, W1, q_b, Qb, 2048, 2048);
  gemm_bf16out<<<dim3(4, 32), dim3(256), 0, stream>>>(X, W2, kvd_b, Lat, 2048, 512);

  cvt_bf16<<<dim3(2048), dim3(256), 0, stream>>>(kvu_w, W1, 2097152);
  gemm_kv<<<dim3(32, 32), dim3(256), 0, stream>>>(Lat, W1, kvu_b, Khat, Vt, 512);

  cvt_bf16<<<dim3(4096), dim3(256), 0, stream>>>(out_w, X, 4194304);
  attn_kernel<<<dim3(512), dim3(256), 0, stream>>>(Qb, Khat, Vt, AO);
  gemm_f32out<<<dim3(16, 32), dim3(256), 0, stream>>>(AO, X, out_b, out, 2048, 2048);
}

// Round 5
// 411.378 us; speedup vs baseline: 1.4457x; 1.0821x over previous
//
#include <hip/hip_runtime.h>

typedef unsigned short u16;
typedef __attribute__((ext_vector_type(8))) __bf16 bf16x8;
typedef __attribute__((ext_vector_type(8))) unsigned short u16x8;
typedef __attribute__((ext_vector_type(4))) float f32x4;
typedef __attribute__((ext_vector_type(16))) float f32x16;

#define BK 32
#define TILE_ELEMS (128 * BK)

__device__ __forceinline__ u16 f32_to_bf16(float f) {
  unsigned int u = __builtin_bit_cast(unsigned int, f);
  u += 0x7fffu + ((u >> 16) & 1u);
  return (u16)(u >> 16);
}

// ---------------- fp32 -> bf16 conversion ----------------
__global__ __launch_bounds__(256) void cvt_bf16(const float* __restrict__ in,
                                                u16* __restrict__ out, int n) {
  int i = (blockIdx.x * 256 + threadIdx.x) * 4;
  if (i >= n) return;
  float4 v = *(const float4*)(in + i);
  ushort4 o;
  o.x = f32_to_bf16(v.x);
  o.y = f32_to_bf16(v.y);
  o.z = f32_to_bf16(v.z);
  o.w = f32_to_bf16(v.w);
  *(ushort4*)(out + i) = o;
}

// ------------- GEMM core: C(128x128) = A_tile(128xK) * B_tile(128xK)^T ------
// Single-barrier double-buffered K-loop: loads for tile k+1 issue before the
// barrier; MFMAs consume buf p; ds_writes stage tile k+1 into buf p^1 after.
// Race audit: writes(p^1)@iter k in (b_k,b_{k+1}); reads(p^1)@iters k-1/k+1 in
// adjacent windows -> barrier-ordered. Same-wave DS ops are in-order.
__device__ __forceinline__ void gemm_core(const u16* __restrict__ A_tile,
                                          const u16* __restrict__ B_tile, int K,
                                          u16* As, u16* Bs, f32x4 acc[4][4]) {
  const int tid = threadIdx.x;
  const int w = tid >> 6, lane = tid & 63;
  const int wm = (w >> 1) << 6, wn = (w & 1) << 6;
  const int quad = lane >> 4, l15 = lane & 15;

  const u16* Ap = A_tile + (tid >> 2) * K + (tid & 3) * 8;
  const u16* Bp = B_tile + (tid >> 2) * K + (tid & 3) * 8;

  // prologue: stage tile 0 into buf 0
  u16x8 ra0 = *(const u16x8*)Ap;
  u16x8 ra1 = *(const u16x8*)(Ap + 64 * K);
  u16x8 rb0 = *(const u16x8*)Bp;
  u16x8 rb1 = *(const u16x8*)(Bp + 64 * K);
  *(u16x8*)(As + tid * 8) = ra0;
  *(u16x8*)(As + (256 + tid) * 8) = ra1;
  *(u16x8*)(Bs + tid * 8) = rb0;
  *(u16x8*)(Bs + (256 + tid) * 8) = rb1;

  int p = 0;
  for (int k0 = 0; k0 < K; k0 += BK) {
    const int kn = (k0 + BK < K) ? (k0 + BK) : 0;  // last iter refetches tile 0 (discarded)
    ra0 = *(const u16x8*)(Ap + kn);
    ra1 = *(const u16x8*)(Ap + 64 * K + kn);
    rb0 = *(const u16x8*)(Bp + kn);
    rb1 = *(const u16x8*)(Bp + 64 * K + kn);
    __syncthreads();
    const u16* Asr = As + p * TILE_ELEMS;
    const u16* Bsr = Bs + p * TILE_ELEMS;
    bf16x8 af[4], bf[4];
#pragma unroll
    for (int i = 0; i < 4; i++)
      af[i] = *(const bf16x8*)(Asr + (wm + i * 16 + l15) * BK + quad * 8);
#pragma unroll
    for (int j = 0; j < 4; j++)
      bf[j] = *(const bf16x8*)(Bsr + (wn + j * 16 + l15) * BK + quad * 8);
#pragma unroll
    for (int i = 0; i < 4; i++)
#pragma unroll
      for (int j = 0; j < 4; j++)
        acc[i][j] =
            __builtin_amdgcn_mfma_f32_16x16x32_bf16(af[i], bf[j], acc[i][j], 0, 0, 0);
    const int pn = p ^ 1;
    u16* Asw = As + pn * TILE_ELEMS;
    u16* Bsw = Bs + pn * TILE_ELEMS;
    *(u16x8*)(Asw + tid * 8) = ra0;
    *(u16x8*)(Asw + (256 + tid) * 8) = ra1;
    *(u16x8*)(Bsw + tid * 8) = rb0;
    *(u16x8*)(Bsw + (256 + tid) * 8) = rb1;
    p = pn;
  }
}

// ---------------- fused q-proj + latent-proj ----------------
// grid (20, 32): bn<16 -> q (N=2048), bn>=16 -> latent (N=512). Uniform branch.
__global__ __launch_bounds__(256) void gemm_qlat(const u16* __restrict__ X,
                                                 const u16* __restrict__ QW,
                                                 const u16* __restrict__ KVDW,
                                                 const float* __restrict__ q_b,
                                                 const float* __restrict__ kvd_b,
                                                 u16* __restrict__ Qb,
                                                 u16* __restrict__ Lat) {
  __shared__ __align__(16) u16 As[2 * TILE_ELEMS];
  __shared__ __align__(16) u16 Bs[2 * TILE_ELEMS];
  const int bn = blockIdx.x, bm = blockIdx.y;
  const bool isq = bn < 16;
  const u16* B_tile = isq ? QW + (size_t)bn * 128 * 2048
                          : KVDW + (size_t)(bn - 16) * 128 * 2048;
  f32x4 acc[4][4];
  const f32x4 z = {0.f, 0.f, 0.f, 0.f};
#pragma unroll
  for (int i = 0; i < 4; i++)
#pragma unroll
    for (int j = 0; j < 4; j++) acc[i][j] = z;
  gemm_core(X + (size_t)bm * 128 * 2048, B_tile, 2048, As, Bs, acc);

  const float* bias = isq ? q_b : kvd_b;
  u16* C = isq ? Qb : Lat;
  const int N = isq ? 2048 : 512;
  const int colbase = (isq ? bn : bn - 16) * 128;

  const int tid = threadIdx.x;
  const int w = tid >> 6, lane = tid & 63;
  const int wm = (w >> 1) << 6, wn = (w & 1) << 6;
  const int quad = lane >> 4, l15 = lane & 15;
  const int row0 = bm * 128 + wm + quad * 4;
  const int col0 = colbase + wn + l15;
#pragma unroll
  for (int i = 0; i < 4; i++)
#pragma unroll
    for (int j = 0; j < 4; j++) {
      int col = col0 + j * 16;
      float bv = bias[col];
#pragma unroll
      for (int r = 0; r < 4; r++) {
        int row = row0 + i * 16 + r;
        C[(size_t)row * N + col] = f32_to_bf16(acc[i][j][r] + bv);
      }
    }
}

// ---------------- GEMM with fp32 output (final projection) ----------------
__global__ __launch_bounds__(256) void gemm_f32out(const u16* __restrict__ A,
                                                   const u16* __restrict__ B,
                                                   const float* __restrict__ bias,
                                                   float* __restrict__ C, int K, int N) {
  __shared__ __align__(16) u16 As[2 * TILE_ELEMS];
  __shared__ __align__(16) u16 Bs[2 * TILE_ELEMS];
  f32x4 acc[4][4];
  const f32x4 z = {0.f, 0.f, 0.f, 0.f};
#pragma unroll
  for (int i = 0; i < 4; i++)
#pragma unroll
    for (int j = 0; j < 4; j++) acc[i][j] = z;
  gemm_core(A + (size_t)blockIdx.y * 128 * K, B + (size_t)blockIdx.x * 128 * K, K,
            As, Bs, acc);

  const int tid = threadIdx.x;
  const int w = tid >> 6, lane = tid & 63;
  const int wm = (w >> 1) << 6, wn = (w & 1) << 6;
  const int quad = lane >> 4, l15 = lane & 15;
  const int row0 = blockIdx.y * 128 + wm + quad * 4;
  const int col0 = blockIdx.x * 128 + wn + l15;
#pragma unroll
  for (int i = 0; i < 4; i++)
#pragma unroll
    for (int j = 0; j < 4; j++) {
      int col = col0 + j * 16;
      float bv = bias[col];
#pragma unroll
      for (int r = 0; r < 4; r++) {
        int row = row0 + i * 16 + r;
        C[(size_t)row * N + col] = acc[i][j][r] + bv;
      }
    }
}

// ------------- GEMM3: kv-up with scatter epilogue: K->(b,h,s,d), V->(b,h,d,s) -
__global__ __launch_bounds__(256) void gemm_kv(const u16* __restrict__ A,
                                               const u16* __restrict__ B,
                                               const float* __restrict__ bias,
                                               u16* __restrict__ Khat,
                                               u16* __restrict__ Vt, int K) {
  __shared__ __align__(16) u16 As[2 * TILE_ELEMS];
  __shared__ __align__(16) u16 Bs[2 * TILE_ELEMS];
  f32x4 acc[4][4];
  const f32x4 z = {0.f, 0.f, 0.f, 0.f};
#pragma unroll
  for (int i = 0; i < 4; i++)
#pragma unroll
    for (int j = 0; j < 4; j++) acc[i][j] = z;
  gemm_core(A + (size_t)blockIdx.y * 128 * K, B + (size_t)blockIdx.x * 128 * K, K,
            As, Bs, acc);

  const int tid = threadIdx.x;
  const int w = tid >> 6, lane = tid & 63;
  const int wm = (w >> 1) << 6, wn = (w & 1) << 6;
  const int quad = lane >> 4, l15 = lane & 15;
  const int row0 = blockIdx.y * 128 + wm + quad * 4;
  const int col0 = blockIdx.x * 128 + wn + l15;
#pragma unroll
  for (int i = 0; i < 4; i++)
#pragma unroll
    for (int j = 0; j < 4; j++) {
      int n = col0 + j * 16;
      float bv = bias[n];
#pragma unroll
      for (int r = 0; r < 4; r++) {
        int row = row0 + i * 16 + r;   // row = b*2048 + s
        int bb = row >> 11, s = row & 2047;
        u16 val = f32_to_bf16(acc[i][j][r] + bv);
        if (n < 2048) {
          int h = n >> 7, d = n & 127;
          Khat[((size_t)(bb * 16 + h) * 2048 + s) * 128 + d] = val;
        } else {
          int h = (n - 2048) >> 7, d = n & 127;
          Vt[((size_t)(bb * 16 + h) * 128 + d) * 2048 + s] = val;
        }
      }
    }
}

// ---------------- attention: 32-row waves, 32x32x16 MFMA, Q in registers ----
__global__ __launch_bounds__(256) void attn_kernel(const u16* __restrict__ Q,
                                                   const u16* __restrict__ Khat,
                                                   const u16* __restrict__ Vt,
                                                   u16* __restrict__ O) {
  __shared__ __align__(16) u16 Ks[64 * 136];      // keys x dims (stride 136)
  __shared__ __align__(16) u16 Vs[128 * 72];      // dims x keys (stride 72)
  __shared__ __align__(16) u16 Ps[4 * 32 * 72];   // per-wave P (32 rows x 64 keys)

  const int tid = threadIdx.x;
  const int w = tid >> 6, lane = tid & 63;
  const int l31 = lane & 31, half = lane >> 5;
  const int qt = blockIdx.x & 15;
  const int h = (blockIdx.x >> 4) & 15;
  const int b = blockIdx.x >> 8;
  const int bh = b * 16 + h;
  const float SC = 0.08838834764831845f * 1.4426950408889634f;  // 1/sqrt(128)*log2(e)

  bf16x8 qf[8];
  {
    const u16* qrow = Q + (size_t)(b * 2048 + qt * 128 + w * 32 + l31) * 2048 +
                      h * 128 + half * 8;
#pragma unroll
    for (int kc = 0; kc < 8; kc++) qf[kc] = *(const bf16x8*)(qrow + kc * 16);
  }

  f32x16 oacc[4];
#pragma unroll
  for (int nt = 0; nt < 4; nt++)
#pragma unroll
    for (int r = 0; r < 16; r++) oacc[nt][r] = 0.f;
  float lsum[16];
#pragma unroll
  for (int r = 0; r < 16; r++) lsum[r] = 0.f;

  const u16* Kg = Khat + (size_t)bh * 2048 * 128;
  const u16* Vg = Vt + (size_t)bh * 128 * 2048;
  u16* Pw = Ps + w * 32 * 72;

  for (int key0 = 0; key0 < 2048; key0 += 64) {
    u16x8 kv[4], vv[4];
#pragma unroll
    for (int it = 0; it < 4; it++) {
      int slot = it * 256 + tid;
      int kr = slot >> 4, c = slot & 15;
      kv[it] = *(const u16x8*)(Kg + (size_t)(key0 + kr) * 128 + c * 8);
    }
#pragma unroll
    for (int it = 0; it < 4; it++) {
      int slot = it * 256 + tid;
      int d = slot >> 3, c = slot & 7;
      vv[it] = *(const u16x8*)(Vg + (size_t)d * 2048 + key0 + c * 8);
    }
    __syncthreads();
#pragma unroll
    for (int it = 0; it < 4; it++) {
      int slot = it * 256 + tid;
      int kr = slot >> 4, c = slot & 15;
      *(u16x8*)(Ks + kr * 136 + c * 8) = kv[it];
    }
#pragma unroll
    for (int it = 0; it < 4; it++) {
      int slot = it * 256 + tid;
      int d = slot >> 3, c = slot & 7;
      *(u16x8*)(Vs + d * 72 + c * 8) = vv[it];
    }
    __syncthreads();

    f32x16 sacc[2];
#pragma unroll
    for (int ct = 0; ct < 2; ct++)
#pragma unroll
      for (int r = 0; r < 16; r++) sacc[ct][r] = 0.f;
#pragma unroll
    for (int ct = 0; ct < 2; ct++)
#pragma unroll
      for (int kc = 0; kc < 8; kc++) {
        bf16x8 kf =
            *(const bf16x8*)(Ks + (ct * 32 + l31) * 136 + kc * 16 + half * 8);
        sacc[ct] =
            __builtin_amdgcn_mfma_f32_32x32x16_bf16(qf[kc], kf, sacc[ct], 0, 0, 0);
      }

#pragma unroll
    for (int ct = 0; ct < 2; ct++)
#pragma unroll
      for (int r = 0; r < 16; r++) {
        float e = exp2f(sacc[ct][r] * SC);
        lsum[r] += e;
        int ridx = (r & 3) + 8 * (r >> 2) + 4 * half;
        Pw[ridx * 72 + ct * 32 + l31] = f32_to_bf16(e);
      }

    bf16x8 pf[4];
#pragma unroll
    for (int kc = 0; kc < 4; kc++)
      pf[kc] = *(const bf16x8*)(Pw + l31 * 72 + kc * 16 + half * 8);
#pragma unroll
    for (int nt = 0; nt < 4; nt++)
#pragma unroll
      for (int kc = 0; kc < 4; kc++) {
        bf16x8 vf =
            *(const bf16x8*)(Vs + (nt * 32 + l31) * 72 + kc * 16 + half * 8);
        oacc[nt] =
            __builtin_amdgcn_mfma_f32_32x32x16_bf16(pf[kc], vf, oacc[nt], 0, 0, 0);
      }
  }

#pragma unroll
  for (int r = 0; r < 16; r++) {
    float s = lsum[r];
    s += __shfl_xor(s, 1);
    s += __shfl_xor(s, 2);
    s += __shfl_xor(s, 4);
    s += __shfl_xor(s, 8);
    s += __shfl_xor(s, 16);
    lsum[r] = 1.0f / s;
  }

#pragma unroll
  for (int nt = 0; nt < 4; nt++)
#pragma unroll
    for (int r = 0; r < 16; r++) {
      int ridx = (r & 3) + 8 * (r >> 2) + 4 * half;
      int row = b * 2048 + qt * 128 + w * 32 + ridx;
      int col = h * 128 + nt * 32 + l31;
      O[(size_t)row * 2048 + col] = f32_to_bf16(oacc[nt][r] * lsum[r]);
    }
}

// ---------------- launch ----------------
extern "C" void kernel_launch(void* const* d_in, const int* in_sizes, int n_in,
                              void* d_out, int out_size, void* d_ws, size_t ws_size,
                              hipStream_t stream) {
  (void)in_sizes; (void)n_in; (void)out_size; (void)ws_size;
  const float* x     = (const float*)d_in[0];
  const float* q_w   = (const float*)d_in[1];
  const float* q_b   = (const float*)d_in[2];
  const float* kvd_w = (const float*)d_in[3];
  const float* kvd_b = (const float*)d_in[4];
  const float* kvu_w = (const float*)d_in[5];
  const float* kvu_b = (const float*)d_in[6];
  const float* out_w = (const float*)d_in[7];
  const float* out_b = (const float*)d_in[8];
  float* out = (float*)d_out;

  char* p = (char*)d_ws;
  u16* X    = (u16*)(p + 0);
  u16* W1   = (u16*)(p + (size_t)16 * 1024 * 1024);
  u16* W2   = (u16*)(p + (size_t)24 * 1024 * 1024);
  u16* Qb   = (u16*)(p + (size_t)26 * 1024 * 1024);
  u16* Lat  = (u16*)(p + (size_t)42 * 1024 * 1024);
  u16* Khat = (u16*)(p + (size_t)46 * 1024 * 1024);
  u16* Vt   = (u16*)(p + (size_t)62 * 1024 * 1024);
  u16* AO   = (u16*)(p + (size_t)78 * 1024 * 1024);

  cvt_bf16<<<dim3(8192), dim3(256), 0, stream>>>(x, X, 8388608);
  cvt_bf16<<<dim3(4096), dim3(256), 0, stream>>>(q_w, W1, 4194304);
  cvt_bf16<<<dim3(1024), dim3(256), 0, stream>>>(kvd_w, W2, 1048576);

  // fused q + latent projection
  gemm_qlat<<<dim3(20, 32), dim3(256), 0, stream>>>(X, W1, W2, q_b, kvd_b, Qb, Lat);

  cvt_bf16<<<dim3(2048), dim3(256), 0, stream>>>(kvu_w, W1, 2097152);
  gemm_kv<<<dim3(32, 32), dim3(256), 0, stream>>>(Lat, W1, kvu_b, Khat, Vt, 512);

  cvt_bf16<<<dim3(4096), dim3(256), 0, stream>>>(out_w, X, 4194304);
  attn_kernel<<<dim3(512), dim3(256), 0, stream>>>(Qb, Khat, Vt, AO);
  gemm_f32out<<<dim3(16, 32), dim3(256), 0, stream>>>(AO, X, out_b, out, 2048, 2048);
}